// Round 7
// baseline (100.910 us; speedup 1.0000x reference)
//
#include <hip/hip_runtime.h>
#include <math.h>

#define BB   64
#define SS   576
#define DD   768
#define KTOP 63
#define KEEP 64
#define HH   128
#define NROW (BB*KEEP + BB)   // 4160 = 65*64 rows through the autoencoder
#define SCH  24               // s-chunk size for k_extra2 (576 = 24*24)

typedef unsigned long long ull;
typedef _Float16 h2 __attribute__((ext_vector_type(2)));

static __device__ __forceinline__ float DOT2(h2 a, h2 b, float c) {
#if __has_builtin(__builtin_amdgcn_fdot2)
  return __builtin_amdgcn_fdot2(a, b, c, false);
#else
  return fmaf((float)a[1], (float)b[1], fmaf((float)a[0], (float)b[0], c));
#endif
}
static __device__ __forceinline__ unsigned PK(float x, float y) {
  return __builtin_bit_cast(unsigned, __builtin_amdgcn_cvt_pkrtz(x, y));
}
static __device__ __forceinline__ h2 BC(unsigned u) {
  return __builtin_bit_cast(h2, u);
}

// ---------------- K1: cls attention scores (f64 accumulate for exact ranking) ---
__global__ __launch_bounds__(256) void k_scores(const float* __restrict__ cls,
                                                const float* __restrict__ fm,
                                                float* __restrict__ scores)
{
  int gw = (blockIdx.x * blockDim.x + threadIdx.x) >> 6;   // one wave per (b,s)
  int lane = threadIdx.x & 63;
  if (gw >= BB * SS) return;
  int b = gw / SS, s = gw - b * SS;
  const float4* frow = (const float4*)(fm + ((size_t)b * SS + s) * DD);
  const float4* crow = (const float4*)(cls + (size_t)b * DD);
  double acc = 0.0;
#pragma unroll
  for (int j = 0; j < 3; ++j) {
    float4 f = frow[lane + 64 * j];
    float4 c = crow[lane + 64 * j];
    acc += (double)f.x * c.x + (double)f.y * c.y + (double)f.z * c.z + (double)f.w * c.w;
  }
#pragma unroll
  for (int off = 32; off > 0; off >>= 1) acc += __shfl_down(acc, off, 64);
  if (lane == 0) scores[(size_t)b * SS + s] = (float)acc;
}

// ---------------- K2: rank-select top-63 + normalized softmax weights ----------
__global__ __launch_bounds__(576) void k_rank(const float* __restrict__ scores,
                                              int* __restrict__ idxout,
                                              float* __restrict__ wprime)
{
  __shared__ ull keys[SS];
  __shared__ float redm[9], redz[9];
  int b = blockIdx.x, tid = threadIdx.x;          // tid == s (0..575)
  int lane = tid & 63, wid = tid >> 6;            // 9 waves
  float sc = scores[(size_t)b * SS + tid];
  unsigned int u = __float_as_uint(sc);
  u = (u & 0x80000000u) ? ~u : (u | 0x80000000u); // order-preserving map
  ull key = ((ull)u << 32) | (ull)(0xFFFFFFFFu - (unsigned)tid);
  keys[tid] = key;
  __syncthreads();
  int rank = 0;
#pragma unroll 8
  for (int s = 0; s < SS; ++s) rank += (keys[s] > key) ? 1 : 0;   // LDS broadcast
  bool sel = rank < KTOP;
  if (sel) idxout[b * KEEP + rank] = tid;
  float m = sel ? -1e30f : sc;
#pragma unroll
  for (int off = 32; off; off >>= 1) m = fmaxf(m, __shfl_xor(m, off, 64));
  if (lane == 0) redm[wid] = m;
  __syncthreads();
  float M = redm[0];
#pragma unroll
  for (int i = 1; i < 9; ++i) M = fmaxf(M, redm[i]);
  float e = sel ? 0.f : expf(sc - M);
  float z = e;
#pragma unroll
  for (int off = 32; off; off >>= 1) z += __shfl_xor(z, off, 64);
  if (lane == 0) redz[wid] = z;
  __syncthreads();
  float Z = redz[0];
#pragma unroll
  for (int i = 1; i < 9; ++i) Z += redz[i];
  wprime[(size_t)b * SS + tid] = e / Z;
}

// ---------------- K2b: partial weighted sums over 24-row chunks ----------------
__global__ __launch_bounds__(192) void k_extra2(const float* __restrict__ wprime,
                                                const float* __restrict__ fm,
                                                float* __restrict__ epart)
{
  int b = blockIdx.x, p = blockIdx.y, tid = threadIdx.x;   // tid = float4 col
  const float* fbase = fm + ((size_t)b * SS + p * SCH) * DD + tid * 4;
  const float* wp = wprime + (size_t)b * SS + p * SCH;
  float4 acc = make_float4(0.f, 0.f, 0.f, 0.f);
#pragma unroll
  for (int r = 0; r < SCH; ++r) {
    float w = wp[r];
    float4 v = *(const float4*)(fbase + (size_t)r * DD);
    acc.x = fmaf(w, v.x, acc.x); acc.y = fmaf(w, v.y, acc.y);
    acc.z = fmaf(w, v.z, acc.z); acc.w = fmaf(w, v.w, acc.w);
  }
  *(float4*)(epart + ((size_t)(b * SCH + p) * DD) + tid * 4) = acc;
}

// ---------------- K2c: reduce 24 partials -> extra token -----------------------
__global__ __launch_bounds__(256) void k_ered(const float* __restrict__ epart,
                                              float* __restrict__ extra)
{
  int i = blockIdx.x * 256 + threadIdx.x;                  // 12288 float4 outputs
  int b = i / (DD / 4), c4 = i - b * (DD / 4);
  const float4* P = (const float4*)epart;
  float4 s = make_float4(0.f, 0.f, 0.f, 0.f);
#pragma unroll
  for (int p = 0; p < SCH; ++p) {
    float4 t = P[(size_t)(b * SCH + p) * (DD / 4) + c4];
    s.x += t.x; s.y += t.y; s.z += t.z; s.w += t.w;
  }
  ((float4*)extra)[i] = s;
}

// ---------------- K3: partial[y] = X(rows) @ W1[K-chunk y]  (f16 dot2) ---------
// Block = 64 rows x 128 cols, 128 threads, 8x8 per-thread tile, K-chunk 64.
// X in LDS as f16 row-major; W1 as k-adjacent half2 pairs (register transpose at
// stage). LDS 25.6 KB. Per 4-K step: 8 b64 + 4 b128 LDS reads feed 128 dot2
// (= 256 FMA) -> 0.25 B/FLOP, dot2 doubles VALU rate.
template<int CPB>
__global__ __launch_bounds__(128) void k_ae1(const float* __restrict__ fm,
                                             const float* __restrict__ cls,
                                             const float* __restrict__ extra,
                                             const int* __restrict__ idxin,
                                             const float* __restrict__ W1,
                                             float* __restrict__ partial)
{
  __shared__ _Float16 Xs[64][68];      // 8.7 KB (pitch 136 B, 8B-aligned)
  __shared__ unsigned Wp[32][132];     // 16.9 KB; Wp[kp][c] = (W[2kp][c],W[2kp+1][c])
  __shared__ const float* rowptr[64];
  int g = blockIdx.x;                  // row group: rows g*64 .. +63
  int tid = threadIdx.x;

  if (tid < 64) {
    const float* p;
    if (g < BB) {
      p = (tid < KTOP) ? fm + ((size_t)g * SS + idxin[g * KEEP + tid]) * DD
                       : extra + (size_t)g * DD;
    } else {
      p = cls + (size_t)tid * DD;
    }
    rowptr[tid] = p;
  }

  int ty = tid >> 4, tx = tid & 15;
  int r0 = ty * 8;
  float acc[8][8] = {};

  for (int cc = 0; cc < CPB; ++cc) {
    int kb = (blockIdx.y * CPB + cc) * 64;
    __syncthreads();                   // rowptr ready / previous tile consumed
#pragma unroll
    for (int i = 0; i < 8; ++i) {      // X tile: 64 rows x 64 k -> f16
      int id = tid + 128 * i;
      int k4 = id & 15, r = id >> 4;
      float4 v = *(const float4*)(rowptr[r] + kb + k4 * 4);
      uint2 o = { PK(v.x, v.y), PK(v.z, v.w) };
      *(uint2*)&Xs[r][k4 * 4] = o;
    }
#pragma unroll
    for (int i = 0; i < 8; ++i) {      // W1 chunk: 32 kp x 128 c half2 pairs
      int id = tid + 128 * i;
      int c4 = id & 31, kp = id >> 5;
      const float* w0 = W1 + (size_t)(kb + 2 * kp) * HH + c4 * 4;
      float4 a = *(const float4*)w0;
      float4 b = *(const float4*)(w0 + HH);
      uint4 o = { PK(a.x, b.x), PK(a.y, b.y), PK(a.z, b.z), PK(a.w, b.w) };
      *(uint4*)&Wp[kp][c4 * 4] = o;
    }
    __syncthreads();
#pragma unroll 4
    for (int q = 0; q < 16; ++q) {     // 4 k per iter
      uint2 xr[8];
#pragma unroll
      for (int i = 0; i < 8; ++i) xr[i] = *(const uint2*)&Xs[r0 + i][q * 4];
      uint4 wa0 = *(const uint4*)&Wp[2 * q][tx * 4];        // k=4q,4q+1 cols 0..3
      uint4 wa1 = *(const uint4*)&Wp[2 * q][64 + tx * 4];   // cols 64+..
      uint4 wb0 = *(const uint4*)&Wp[2 * q + 1][tx * 4];    // k=4q+2,4q+3
      uint4 wb1 = *(const uint4*)&Wp[2 * q + 1][64 + tx * 4];
#pragma unroll
      for (int i = 0; i < 8; ++i) {
        h2 a0 = BC(xr[i].x), a1 = BC(xr[i].y);
        acc[i][0] = DOT2(a1, BC(wb0.x), DOT2(a0, BC(wa0.x), acc[i][0]));
        acc[i][1] = DOT2(a1, BC(wb0.y), DOT2(a0, BC(wa0.y), acc[i][1]));
        acc[i][2] = DOT2(a1, BC(wb0.z), DOT2(a0, BC(wa0.z), acc[i][2]));
        acc[i][3] = DOT2(a1, BC(wb0.w), DOT2(a0, BC(wa0.w), acc[i][3]));
        acc[i][4] = DOT2(a1, BC(wb1.x), DOT2(a0, BC(wa1.x), acc[i][4]));
        acc[i][5] = DOT2(a1, BC(wb1.y), DOT2(a0, BC(wa1.y), acc[i][5]));
        acc[i][6] = DOT2(a1, BC(wb1.z), DOT2(a0, BC(wa1.z), acc[i][6]));
        acc[i][7] = DOT2(a1, BC(wb1.w), DOT2(a0, BC(wa1.w), acc[i][7]));
      }
    }
  }
  float* P = partial + (size_t)(CPB == 1 ? blockIdx.y : 0) * ((size_t)NROW * HH);
#pragma unroll
  for (int i = 0; i < 8; ++i) {
    size_t row = (size_t)(g * 64 + r0 + i);
    float4 v0 = make_float4(acc[i][0], acc[i][1], acc[i][2], acc[i][3]);
    float4 v1 = make_float4(acc[i][4], acc[i][5], acc[i][6], acc[i][7]);
    *(float4*)&P[row * HH + tx * 4] = v0;
    *(float4*)&P[row * HH + 64 + tx * 4] = v1;
  }
}

// ---------------- K3b: H(f16) = tanh(sum(partials) + b1) -----------------------
template<int NP>
__global__ __launch_bounds__(256) void k_hred(const float* __restrict__ partial,
                                              const float* __restrict__ b1,
                                              unsigned* __restrict__ H16)
{
  int i4 = blockIdx.x * 256 + threadIdx.x;          // float4 index, 133120 total
  const float4* P = (const float4*)partial;
  float4 s = P[i4];
#pragma unroll
  for (int p = 1; p < NP; ++p) {
    float4 t = P[(size_t)p * (NROW * HH / 4) + i4];
    s.x += t.x; s.y += t.y; s.z += t.z; s.w += t.w;
  }
  float4 bv = ((const float4*)b1)[i4 & 31];         // HH/4 = 32 float4 per row
  s.x = tanhf(s.x + bv.x); s.y = tanhf(s.y + bv.y);
  s.z = tanhf(s.z + bv.z); s.w = tanhf(s.w + bv.w);
  uint2 o = { PK(s.x, s.y), PK(s.z, s.w) };
  ((uint2*)H16)[i4] = o;
}

// ---------------- K4: out = H @ W2 + b2  (f16 dot2) ----------------------------
// Block = 64 rows x 128 cols, 128 threads, 8x8 tile, K=128 single stage.
// LDS 50.7 KB -> 3 blocks/CU. grid (65, 6).
__global__ __launch_bounds__(128) void k_ae2(const unsigned* __restrict__ H16,
                                             const float* __restrict__ W2,
                                             const float* __restrict__ b2,
                                             float* __restrict__ out)
{
  __shared__ _Float16 Hs[64][132];     // 16.9 KB (pitch 264 B)
  __shared__ unsigned Wp[64][132];     // 33.8 KB
  int g = blockIdx.x, cb = blockIdx.y, tid = threadIdx.x;

#pragma unroll
  for (int i = 0; i < 16; ++i) {       // H tile: 64 rows x 128 k f16 (copy)
    int id = tid + 128 * i;
    int k4 = id & 31, r = id >> 5;
    uint2 v = ((const uint2*)H16)[(size_t)(g * 64 + r) * (HH / 4) + k4];
    *(uint2*)&Hs[r][k4 * 4] = v;
  }
#pragma unroll
  for (int i = 0; i < 16; ++i) {       // W2 slice: 64 kp x 128 c half2 pairs
    int id = tid + 128 * i;
    int c4 = id & 31, kp = id >> 5;
    const float* w0 = W2 + (size_t)(2 * kp) * DD + cb * 128 + c4 * 4;
    float4 a = *(const float4*)w0;
    float4 b = *(const float4*)(w0 + DD);
    uint4 o = { PK(a.x, b.x), PK(a.y, b.y), PK(a.z, b.z), PK(a.w, b.w) };
    *(uint4*)&Wp[kp][c4 * 4] = o;
  }
  __syncthreads();

  int ty = tid >> 4, tx = tid & 15;
  int r0 = ty * 8;
  float acc[8][8] = {};
#pragma unroll 4
  for (int q = 0; q < 32; ++q) {       // K = 128, 4 k per iter
    uint2 xr[8];
#pragma unroll
    for (int i = 0; i < 8; ++i) xr[i] = *(const uint2*)&Hs[r0 + i][q * 4];
    uint4 wa0 = *(const uint4*)&Wp[2 * q][tx * 4];
    uint4 wa1 = *(const uint4*)&Wp[2 * q][64 + tx * 4];
    uint4 wb0 = *(const uint4*)&Wp[2 * q + 1][tx * 4];
    uint4 wb1 = *(const uint4*)&Wp[2 * q + 1][64 + tx * 4];
#pragma unroll
    for (int i = 0; i < 8; ++i) {
      h2 a0 = BC(xr[i].x), a1 = BC(xr[i].y);
      acc[i][0] = DOT2(a1, BC(wb0.x), DOT2(a0, BC(wa0.x), acc[i][0]));
      acc[i][1] = DOT2(a1, BC(wb0.y), DOT2(a0, BC(wa0.y), acc[i][1]));
      acc[i][2] = DOT2(a1, BC(wb0.z), DOT2(a0, BC(wa0.z), acc[i][2]));
      acc[i][3] = DOT2(a1, BC(wb0.w), DOT2(a0, BC(wa0.w), acc[i][3]));
      acc[i][4] = DOT2(a1, BC(wb1.x), DOT2(a0, BC(wa1.x), acc[i][4]));
      acc[i][5] = DOT2(a1, BC(wb1.y), DOT2(a0, BC(wa1.y), acc[i][5]));
      acc[i][6] = DOT2(a1, BC(wb1.z), DOT2(a0, BC(wa1.z), acc[i][6]));
      acc[i][7] = DOT2(a1, BC(wb1.w), DOT2(a0, BC(wa1.w), acc[i][7]));
    }
  }
  float4 bv0 = *(const float4*)&b2[cb * 128 + tx * 4];
  float4 bv1 = *(const float4*)&b2[cb * 128 + 64 + tx * 4];
#pragma unroll
  for (int i = 0; i < 8; ++i) {
    size_t row = (size_t)(g * 64 + r0 + i);
    float4 y0 = make_float4(acc[i][0] + bv0.x, acc[i][1] + bv0.y,
                            acc[i][2] + bv0.z, acc[i][3] + bv0.w);
    float4 y1 = make_float4(acc[i][4] + bv1.x, acc[i][5] + bv1.y,
                            acc[i][6] + bv1.z, acc[i][7] + bv1.w);
    *(float4*)&out[row * DD + cb * 128 + tx * 4] = y0;
    *(float4*)&out[row * DD + cb * 128 + 64 + tx * 4] = y1;
  }
}

extern "C" void kernel_launch(void* const* d_in, const int* in_sizes, int n_in,
                              void* d_out, int out_size, void* d_ws, size_t ws_size,
                              hipStream_t stream)
{
  const float* cls = (const float*)d_in[0];
  const float* fm  = (const float*)d_in[1];
  const float* W1  = (const float*)d_in[2];
  const float* b1  = (const float*)d_in[3];
  const float* W2  = (const float*)d_in[4];
  const float* b2  = (const float*)d_in[5];
  float* out = (float*)d_out;

  char* ws = (char*)d_ws;
  float* scores  = (float*)ws;                          // 147456 B
  int*   idx     = (int*)(ws + 147456);                 //  16384 B
  float* extra   = (float*)(ws + 163840);               // 196608 B
  float* wprime  = (float*)(ws + 360448);               // 147456 B
  float* epart   = (float*)(ws + 507904);               // 4718592 B
  float* partial = (float*)(ws + 5226496);              // NP slices of 2129920 B
  const size_t PSLICE = (size_t)NROW * HH * 4;          // 2129920 B
  const size_t H16SZ  = (size_t)NROW * HH * 2;          // 1064960 B

  hipLaunchKernelGGL(k_scores, dim3((BB * SS) / 4), dim3(256), 0, stream, cls, fm, scores);
  hipLaunchKernelGGL(k_rank,   dim3(BB),            dim3(576), 0, stream, scores, idx, wprime);
  hipLaunchKernelGGL(k_extra2, dim3(BB, SCH),       dim3(192), 0, stream, wprime, fm, epart);
  hipLaunchKernelGGL(k_ered,   dim3(BB * DD / 1024), dim3(256), 0, stream, epart, extra);

  if (ws_size >= 5226496 + 12 * PSLICE + H16SZ) {       // 12 partials + H16
    unsigned* H16 = (unsigned*)(ws + 5226496 + 12 * PSLICE);
    hipLaunchKernelGGL(k_ae1<1>,  dim3(65, 12),      dim3(128), 0, stream,
                       fm, cls, extra, idx, W1, partial);
    hipLaunchKernelGGL(k_hred<12>, dim3(NROW * HH / 1024), dim3(256), 0, stream,
                       partial, b1, H16);
    hipLaunchKernelGGL(k_ae2,     dim3(65, 6),       dim3(128), 0, stream, H16, W2, b2, out);
  } else {                                              // small-ws fallback
    unsigned* H16 = (unsigned*)(ws + 5226496 + PSLICE);
    hipLaunchKernelGGL(k_ae1<12>, dim3(65, 1),       dim3(128), 0, stream,
                       fm, cls, extra, idx, W1, partial);
    hipLaunchKernelGGL(k_hred<1>, dim3(NROW * HH / 1024), dim3(256), 0, stream,
                       partial, b1, H16);
    hipLaunchKernelGGL(k_ae2,     dim3(65, 6),       dim3(128), 0, stream, H16, W2, b2, out);
  }
}